// Round 1
// 345.138 us; speedup vs baseline: 1.0464x; 1.0464x over previous
//
#include <hip/hip_runtime.h>

#define NN 100000
#define DD 128
#define EE 640000
#define NPAD 100352  // NN rounded up to 256 multiple

typedef __bf16 bf16x8 __attribute__((ext_vector_type(8)));
typedef float floatx4 __attribute__((ext_vector_type(4)));

__device__ __forceinline__ unsigned short f2bf(float f) {
    unsigned int u = __float_as_uint(f);
    u += 0x7FFF + ((u >> 16) & 1);   // round-to-nearest-even
    return (unsigned short)(u >> 16);
}

// ---------------------------------------------------------------------------
// CSR build: histogram -> 3-kernel exclusive scan -> bucket scatter
// ---------------------------------------------------------------------------
__global__ __launch_bounds__(256) void hist_k(const int* __restrict__ ei,
                                              int* __restrict__ deg) {
    int e = blockIdx.x * 256 + threadIdx.x;
    if (e < EE) atomicAdd(&deg[ei[EE + e]], 1);
}

__global__ __launch_bounds__(256) void scan1_k(const int* __restrict__ deg,
                                               int* __restrict__ exc,
                                               int* __restrict__ chunkSums) {
    __shared__ int s[256];
    int t = threadIdx.x, g = blockIdx.x * 256 + t;
    int v = (g < NN) ? deg[g] : 0;
    s[t] = v;
    __syncthreads();
    for (int off = 1; off < 256; off <<= 1) {
        int u = (t >= off) ? s[t - off] : 0;
        __syncthreads();
        s[t] += u;
        __syncthreads();
    }
    if (g < NN) exc[g] = s[t] - v;
    if (t == 255) chunkSums[blockIdx.x] = s[255];
}

__global__ __launch_bounds__(512) void scan2_k(int* __restrict__ chunkSums, int n) {
    __shared__ int s[512];
    int t = threadIdx.x;
    int v = (t < n) ? chunkSums[t] : 0;
    s[t] = v;
    __syncthreads();
    for (int off = 1; off < 512; off <<= 1) {
        int u = (t >= off) ? s[t - off] : 0;
        __syncthreads();
        s[t] += u;
        __syncthreads();
    }
    if (t < n) chunkSums[t] = s[t] - v;  // exclusive
}

__global__ __launch_bounds__(256) void scan3_k(int* __restrict__ exc,
                                               const int* __restrict__ chunkSums,
                                               int* __restrict__ cursor) {
    int g = blockIdx.x * 256 + threadIdx.x;
    if (g < NN) {
        int o = exc[g] + chunkSums[blockIdx.x];
        exc[g] = o;
        cursor[g] = o;
    }
}

__global__ __launch_bounds__(256) void esort_k(const int* __restrict__ ei,
                                               int* __restrict__ cursor,
                                               int* __restrict__ ssrc) {
    int e = blockIdx.x * 256 + threadIdx.x;
    if (e >= EE) return;
    int pos = atomicAdd(&cursor[ei[EE + e]], 1);
    ssrc[pos] = ei[e];
}

// ---------------------------------------------------------------------------
// aggregate + fuse: h[node] = bf16((1+eps)*x[node] + sum_{src in CSR} x[src])
// 32 lanes (float4) per node. Latency-bound before: 1 dependent gather chain
// per edge. Now: 4-wide predicated unroll -> 4 independent row gathers in
// flight per iteration (no serial remainder loop; duplicate s0 rows on the
// tail iteration hit L1 and are masked by m1/m2/m3).
// ---------------------------------------------------------------------------
__global__ __launch_bounds__(256) void aggregate_k(
    const float4* __restrict__ x4, const int* __restrict__ ssrc,
    const int* __restrict__ offs, const int* __restrict__ deg,
    const float* __restrict__ epsp, ushort4* __restrict__ hout) {
    int tid = blockIdx.x * 256 + threadIdx.x;
    int node = tid >> 5, lane = tid & 31;
    if (node >= NN) return;
    int start = offs[node], d = deg[node];
    float ef = 1.0f + epsp[0];
    float4 v = x4[node * 32 + lane];
    float ax = ef * v.x, ay = ef * v.y, az = ef * v.z, aw = ef * v.w;
    for (int j = 0; j < d; j += 4) {
        int r = d - j;          // >= 1
        int b = start + j;
        int s0 = ssrc[b];
        int s1 = ssrc[b + ((r > 1) ? 1 : 0)];
        int s2 = ssrc[b + ((r > 2) ? 2 : 0)];
        int s3 = ssrc[b + ((r > 3) ? 3 : 0)];
        float4 xa = x4[s0 * 32 + lane];
        float4 xb = x4[s1 * 32 + lane];
        float4 xc = x4[s2 * 32 + lane];
        float4 xd = x4[s3 * 32 + lane];
        float m1 = (r > 1) ? 1.f : 0.f;
        float m2 = (r > 2) ? 1.f : 0.f;
        float m3 = (r > 3) ? 1.f : 0.f;
        ax += xa.x; ay += xa.y; az += xa.z; aw += xa.w;
        ax += m1 * xb.x; ay += m1 * xb.y; az += m1 * xb.z; aw += m1 * xb.w;
        ax += m2 * xc.x; ay += m2 * xc.y; az += m2 * xc.z; aw += m2 * xc.w;
        ax += m3 * xd.x; ay += m3 * xd.y; az += m3 * xd.z; aw += m3 * xd.w;
    }
    ushort4 u;
    u.x = f2bf(ax); u.y = f2bf(ay); u.z = f2bf(az); u.w = f2bf(aw);
    hout[node * 32 + lane] = u;
}

// ---------------------------------------------------------------------------
// fused GEMM + bias + BN-stat accumulation.
// FUSE_BN=0: A = bf16 hin [N,128] row-major.
// FUSE_BN=1: A = fp32 yin with BN(statsIn,g,beta)+ReLU applied in the staging
//            loader (scale/shift computed per-block from statsIn; no extra
//            kernel, no intermediate bf16 buffer round-trip).
// y = A @ W^T + b (fp32), statsOut[c] += col-sum, statsOut[128+c] += col-sumsq
// ---------------------------------------------------------------------------
template <int FUSE_BN>
__global__ __launch_bounds__(256, 2) void gin_gemm_k(
    const unsigned short* __restrict__ hin,
    const float* __restrict__ yin,
    const float* __restrict__ statsIn,
    const float* __restrict__ gmm,
    const float* __restrict__ bta,
    const float* __restrict__ W, const float* __restrict__ bias,
    float* __restrict__ y, float* __restrict__ statsOut) {
    __shared__ __align__(16) unsigned short Ah[128][136];  // +8 pad
    __shared__ __align__(16) unsigned short Bw[128][136];
    __shared__ __align__(16) float s_sum[128];
    __shared__ __align__(16) float s_sq[128];
    __shared__ __align__(16) float sc[128];
    __shared__ __align__(16) float sh[128];

    const int tid = threadIdx.x;
    const int rowBase = blockIdx.x * 128;

    if (tid < 128) {
        s_sum[tid] = 0.f;
        s_sq[tid] = 0.f;
        if (FUSE_BN) {
            const float inv = 1.0f / (float)NN;
            float mean = statsIn[tid] * inv;
            float var = statsIn[128 + tid] * inv - mean * mean;
            float s = gmm[tid] * rsqrtf(var + 1e-5f);
            sc[tid] = s;
            sh[tid] = bta[tid] - mean * s;
        }
    }

    // stage W (row-major [out][k]) as bf16; B-fragment row n = W row n
    const float4* W4 = (const float4*)W;
#pragma unroll
    for (int j = 0; j < 16; ++j) {
        int f4 = j * 256 + tid;
        int row = f4 >> 5, k4 = f4 & 31;
        float4 wv = W4[f4];
        ushort4 u;
        u.x = f2bf(wv.x); u.y = f2bf(wv.y); u.z = f2bf(wv.z); u.w = f2bf(wv.w);
        *(ushort4*)&Bw[row][k4 * 4] = u;
    }

    if (FUSE_BN) {
        __syncthreads();  // sc/sh ready before the A stage reads them
        const float4* y4in = (const float4*)yin;
#pragma unroll
        for (int j = 0; j < 16; ++j) {
            int c = j * 256 + tid;
            int row = c >> 5, c4 = c & 31;
            int rg = rowBase + row;
            ushort4 u = make_ushort4(0, 0, 0, 0);
            if (rg < NN) {
                float4 v = y4in[rg * 32 + c4];
                float4 s4 = ((const float4*)sc)[c4];
                float4 b4 = ((const float4*)sh)[c4];
                u.x = f2bf(fmaxf(v.x * s4.x + b4.x, 0.f));
                u.y = f2bf(fmaxf(v.y * s4.y + b4.y, 0.f));
                u.z = f2bf(fmaxf(v.z * s4.z + b4.z, 0.f));
                u.w = f2bf(fmaxf(v.w * s4.w + b4.w, 0.f));
            }
            *(ushort4*)&Ah[row][c4 * 4] = u;
        }
    } else {
        const int4* h16 = (const int4*)hin;
#pragma unroll
        for (int j = 0; j < 8; ++j) {
            int c = j * 256 + tid;
            int row = c >> 4, c8 = c & 15;
            int rg = rowBase + row;
            int4 v = make_int4(0, 0, 0, 0);
            if (rg < NN) v = h16[rg * 16 + c8];
            *(int4*)&Ah[row][c8 * 8] = v;
        }
    }

    __syncthreads();

    const int l = tid & 63, w = tid >> 6;
    const int m = l & 15, q = l >> 4;

    floatx4 acc[2][8];
#pragma unroll
    for (int rt = 0; rt < 2; ++rt)
#pragma unroll
        for (int ct = 0; ct < 8; ++ct) acc[rt][ct] = (floatx4)0.0f;

#pragma unroll
    for (int kc = 0; kc < 4; ++kc) {
        int k0 = kc * 32 + q * 8;
        bf16x8 a0 = *(const bf16x8*)&Ah[w * 32 + m][k0];
        bf16x8 a1 = *(const bf16x8*)&Ah[w * 32 + 16 + m][k0];
#pragma unroll
        for (int ct = 0; ct < 8; ++ct) {
            bf16x8 b = *(const bf16x8*)&Bw[ct * 16 + m][k0];
            acc[0][ct] = __builtin_amdgcn_mfma_f32_16x16x32_bf16(a0, b, acc[0][ct], 0, 0, 0);
            acc[1][ct] = __builtin_amdgcn_mfma_f32_16x16x32_bf16(a1, b, acc[1][ct], 0, 0, 0);
        }
    }

    // epilogue: bias, store y, per-column partial stats (mask padding rows)
#pragma unroll
    for (int ct = 0; ct < 8; ++ct) {
        int col = ct * 16 + m;
        float bc = bias[col];
        float ps = 0.f, pq = 0.f;
#pragma unroll
        for (int rt = 0; rt < 2; ++rt) {
#pragma unroll
            for (int i = 0; i < 4; ++i) {
                int rg = rowBase + w * 32 + rt * 16 + q * 4 + i;
                if (rg < NN) {
                    float yv = acc[rt][ct][i] + bc;
                    y[rg * 128 + col] = yv;
                    ps += yv;
                    pq += yv * yv;
                }
            }
        }
        atomicAdd(&s_sum[col], ps);
        atomicAdd(&s_sq[col], pq);
    }
    __syncthreads();
    if (tid < 128) {
        unsafeAtomicAdd(&statsOut[tid], s_sum[tid]);
        unsafeAtomicAdd(&statsOut[128 + tid], s_sq[tid]);
    }
}

// ---------------------------------------------------------------------------
// BN(train, biased var) + ReLU.  OUT_BF16: write bf16 (h1) else fp32 in place
// ---------------------------------------------------------------------------
template <int OUT_BF16>
__global__ __launch_bounds__(256) void bn_relu_k(
    const float* __restrict__ y, const float* __restrict__ stats,
    const float* __restrict__ g, const float* __restrict__ beta,
    float* outf, unsigned short* __restrict__ outh) {
    __shared__ __align__(16) float sc[128];
    __shared__ __align__(16) float sh[128];
    int t = threadIdx.x;
    if (t < 128) {
        const float inv = 1.0f / (float)NN;
        float mean = stats[t] * inv;
        float var = stats[128 + t] * inv - mean * mean;
        float s = g[t] * rsqrtf(var + 1e-5f);
        sc[t] = s;
        sh[t] = beta[t] - mean * s;
    }
    __syncthreads();
    const int total4 = NN * 32;
    const float4* y4 = (const float4*)y;
    for (int i = blockIdx.x * 256 + t; i < total4; i += gridDim.x * 256) {
        int c4 = i & 31;
        float4 v = y4[i];
        float4 s = ((const float4*)sc)[c4];
        float4 b = ((const float4*)sh)[c4];
        float r0 = fmaxf(v.x * s.x + b.x, 0.f);
        float r1 = fmaxf(v.y * s.y + b.y, 0.f);
        float r2 = fmaxf(v.z * s.z + b.z, 0.f);
        float r3 = fmaxf(v.w * s.w + b.w, 0.f);
        if (OUT_BF16) {
            ushort4 u;
            u.x = f2bf(r0); u.y = f2bf(r1); u.z = f2bf(r2); u.w = f2bf(r3);
            ((ushort4*)outh)[i] = u;
        } else {
            ((float4*)outf)[i] = make_float4(r0, r1, r2, r3);
        }
    }
}

// ---------------------------------------------------------------------------
extern "C" void kernel_launch(void* const* d_in, const int* in_sizes, int n_in,
                              void* d_out, int out_size, void* d_ws, size_t ws_size,
                              hipStream_t stream) {
    const float* x   = (const float*)d_in[0];
    const int* ei    = (const int*)d_in[1];   // int64 in ref -> int32 from harness
    const float* eps = (const float*)d_in[2];
    const float* W1  = (const float*)d_in[3];
    const float* b1  = (const float*)d_in[4];
    const float* g1  = (const float*)d_in[5];
    const float* be1 = (const float*)d_in[6];
    const float* W2  = (const float*)d_in[7];
    const float* b2  = (const float*)d_in[8];
    const float* g2  = (const float*)d_in[9];
    const float* be2 = (const float*)d_in[10];
    float* out = (float*)d_out;

    // Workspace layout:
    int* deg        = (int*)d_ws;           // NPAD
    int* offs       = deg + NPAD;           // NPAD
    int* cursor     = offs + NPAD;          // NPAD
    int* chunkSums  = cursor + NPAD;        // 512
    int* ssrc       = chunkSums + 512;      // EE + pad
    unsigned short* hbuf = (unsigned short*)(ssrc + EE + 256);  // N*D bf16
    float* stats    = (float*)(hbuf + (size_t)NN * DD);         // 512
    float* ybuf     = stats + 512;                              // N*D fp32 (fused path)
    size_t need     = (size_t)((char*)(ybuf + (size_t)NN * DD) - (char*)d_ws);
    const bool fused = ws_size >= need;  // ~81 MB; else fall back to 4-kernel tail

    hipMemsetAsync(deg, 0, NPAD * sizeof(int), stream);
    hipMemsetAsync(stats, 0, 512 * sizeof(float), stream);

    const int numChunks = (NN + 255) / 256;  // 391
    hist_k<<<(EE + 255) / 256, 256, 0, stream>>>(ei, deg);
    scan1_k<<<numChunks, 256, 0, stream>>>(deg, offs, chunkSums);
    scan2_k<<<1, 512, 0, stream>>>(chunkSums, numChunks);
    scan3_k<<<numChunks, 256, 0, stream>>>(offs, chunkSums, cursor);
    esort_k<<<(EE + 255) / 256, 256, 0, stream>>>(ei, cursor, ssrc);
    aggregate_k<<<(NN * 32 + 255) / 256, 256, 0, stream>>>(
        (const float4*)x, ssrc, offs, deg, eps, (ushort4*)hbuf);

    int gblocks = (NN + 127) / 128;  // 782
    if (fused) {
        // gemm1 -> ybuf (ws); gemm2 stages BN1+ReLU from ybuf -> out; BN2 in place
        gin_gemm_k<0><<<gblocks, 256, 0, stream>>>(
            hbuf, nullptr, nullptr, nullptr, nullptr, W1, b1, ybuf, stats);
        gin_gemm_k<1><<<gblocks, 256, 0, stream>>>(
            nullptr, ybuf, stats, g1, be1, W2, b2, out, stats + 256);
        bn_relu_k<0><<<4096, 256, 0, stream>>>(out, stats + 256, g2, be2, out, nullptr);
    } else {
        gin_gemm_k<0><<<gblocks, 256, 0, stream>>>(
            hbuf, nullptr, nullptr, nullptr, nullptr, W1, b1, out, stats);
        bn_relu_k<1><<<4096, 256, 0, stream>>>(out, stats, g1, be1, nullptr, hbuf);
        gin_gemm_k<0><<<gblocks, 256, 0, stream>>>(
            hbuf, nullptr, nullptr, nullptr, nullptr, W2, b2, out, stats + 256);
        bn_relu_k<0><<<4096, 256, 0, stream>>>(out, stats + 256, g2, be2, out, nullptr);
    }
}